// Round 1
// baseline (62518.707 us; speedup 1.0000x reference)
//
#include <hip/hip_runtime.h>
#include <hip/hip_cooperative_groups.h>

namespace cg = cooperative_groups;

#define EPSF 1e-8f

// dims
// T=512 B=64 IN=256 OUT=256 H=512 N=2048 C=64 R=4, DREC = 256+512+64 = 832

struct Params {
  const float* Wrec2;    // [256 blocks][832 rows][8 cols] interleaved
  const float* b_lstm;   // 2048
  const float* W_out;    // 512x256
  const float* b_out;    // 256
  const float* W_key;    // 512x64
  const float* b_key;    // 64
  const float* W_beta;   // 512
  const float* b_beta;   // 1
  const float* W_gen;    // 512x64
  const float* b_gen;    // 64
  float* mem;            // [64][2048][64]
  float* hT;             // [2][512][64]   (row-major j, inner b)
  float* cT;             // [512][64]
  float* ebuf;           // [2][64][2048]
  float* keybT;          // [2][64][64]    ([c][b])
  float* AccT;           // [2][64][64]    ([c][b])
  float* Zb;             // [2][64]
  float* S2b;            // [2][64]
  float* loss;           // 1
  float* out;            // d_out: [512][64][256] y (+1 loss); also used as xT[t][in][b] before y[t] written
};

__device__ __forceinline__ float sigm(float x) { return 1.f / (1.f + __expf(-x)); }

__global__ void __launch_bounds__(512) dnc_main(Params P) {
  cg::grid_group grid = cg::this_grid();
  const int tid  = threadIdx.x;
  const int bid  = blockIdx.x;
  const int lane = tid & 63;
  const int wv   = tid >> 6;      // 0..7

  __shared__ union {
    struct { float rT[4096]; float red2[8][8][64]; float gates[8][64]; } a;
    struct { float key[64]; float kp[64]; float red[8][64]; float part[8]; float scal[4]; } m;
  } sh;

  const int b_my  = bid >> 2;     // batch for phase B
  const int chunk = bid & 3;      // 512-slot chunk within batch

  for (int t = 0; t < 512; ++t) {
    const int p = t & 1, pp = p ^ 1;
    //================ phase A: finalize r_{t-1}, LSTM -> h_t ================
    {
      if (t == 0) {
        for (int i = tid; i < 4096; i += 512) sh.a.rT[i] = 0.f;
      } else {
        const float* Acc = P.AccT + pp * 4096;
        const float* kb  = P.keybT + pp * 4096;
        const float* Zp_ = P.Zb + pp * 64;
        const float* S2_ = P.S2b + pp * 64;
        for (int i = tid; i < 4096; i += 512) {
          int bb = i & 63;
          float invZ = 1.f / Zp_[bb];
          sh.a.rT[i] = Acc[i] * invZ + S2_[bb] * invZ * invZ * kb[i];
        }
      }
      // zero next-parity accumulators (blocks 0..8 cover 4224 slots)
      if (bid < 9) {
        int zid = bid * 512 + tid;
        if (zid < 4096)       P.AccT[p*4096 + zid] = 0.f;
        else if (zid < 4160)  P.Zb[p*64 + (zid-4096)] = 0.f;
        else if (zid < 4224)  P.S2b[p*64 + (zid-4160)] = 0.f;
      }
      __syncthreads();

      // outer-product GEMM: block owns 8 cols (2 j x 4 gates); wave wv owns rows [wv*104, +104)
      const float* w8 = P.Wrec2 + (size_t)bid * (832*8);
      const float* xp = P.out + (size_t)t * (256*64);
      const float* hp = P.hT + pp * 32768;
      float acc[8] = {0,0,0,0,0,0,0,0};
      const int r0 = wv * 104, r1 = r0 + 104;
      for (int rr = r0; rr < r1; ++rr) {
        float v;
        if (rr < 256)       v = xp[rr*64 + lane];
        else if (rr < 768)  v = hp[(rr-256)*64 + lane];
        else                v = sh.a.rT[(rr-768)*64 + lane];
        const float* wr = w8 + (size_t)rr * 8;
        #pragma unroll
        for (int k = 0; k < 8; ++k) acc[k] = fmaf(v, wr[k], acc[k]);
      }
      #pragma unroll
      for (int k = 0; k < 8; ++k) sh.a.red2[wv][k][lane] = acc[k];
      __syncthreads();
      {
        const int cidx = wv;
        float gv = 0.f;
        #pragma unroll
        for (int uu = 0; uu < 8; ++uu) gv += sh.a.red2[uu][cidx][lane];
        const int g = cidx & 3, jl = cidx >> 2;
        const int col = g*512 + bid*2 + jl;
        sh.a.gates[cidx][lane] = gv + P.b_lstm[col];
      }
      __syncthreads();
      if (tid < 128) {
        const int bb = tid & 63, jl = tid >> 6;
        const float gi = sh.a.gates[jl*4 + 0][bb];
        const float gf = sh.a.gates[jl*4 + 1][bb];
        const float gg = sh.a.gates[jl*4 + 2][bb];
        const float go = sh.a.gates[jl*4 + 3][bb];
        const int idx = (bid*2 + jl)*64 + bb;
        float cn = sigm(gf) * P.cT[idx] + sigm(gi) * tanhf(gg);
        float hn = sigm(go) * tanhf(cn);
        P.cT[idx] = cn;
        P.hT[p*32768 + idx] = hn;
      }
    }
    grid.sync();
    //================ phase B: fused memory pass + y + loss ================
    {
      const int b = b_my, c = lane;
      const float* hp = P.hT + p * 32768;
      // key partials: wave wv covers j in [wv*64, +64)
      float pk = 0.f;
      #pragma unroll 4
      for (int jj = wv*64; jj < wv*64 + 64; ++jj)
        pk = fmaf(hp[jj*64 + b], P.W_key[jj*64 + c], pk);
      sh.m.red[wv][c] = pk;
      // beta partial: one j per thread
      {
        float pb = hp[tid*64 + b] * P.W_beta[tid];
        #pragma unroll
        for (int off = 32; off; off >>= 1) pb += __shfl_down(pb, off);
        if (lane == 0) sh.m.part[wv] = pb;
      }
      __syncthreads();
      if (tid < 64) {
        float kv = P.b_key[c];
        #pragma unroll
        for (int qq = 0; qq < 8; ++qq) kv += sh.m.red[qq][c];
        sh.m.key[c] = kv;
        if (chunk == 0) P.keybT[p*4096 + c*64 + b] = kv;   // key_t for next step's r-finalize / pending
      } else if (wv == 1) {
        sh.m.kp[lane] = (t > 0) ? P.keybT[pp*4096 + lane*64 + b] : 0.f;
      } else if (tid == 128) {
        sh.m.scal[1] = (t > 0) ? (1.f / P.Zb[pp*64 + b]) : 0.f;
      } else if (tid == 192) {
        float s = P.b_beta[0];
        #pragma unroll
        for (int k = 0; k < 8; ++k) s += sh.m.part[k];
        sh.m.scal[0] = (s > 20.f) ? s : log1pf(__expf(s));  // softplus
      }
      __syncthreads();
      if (tid < 64) {
        float kv = sh.m.key[c];
        float sq = kv * kv;
        #pragma unroll
        for (int off = 32; off; off >>= 1) sq += __shfl_down(sq, off);
        if (c == 0) sh.m.scal[2] = fmaxf(sqrtf(sq), EPSF);  // max(||key||, eps)
      }
      __syncthreads();

      const float beta  = sh.m.scal[0];
      const float invZp = sh.m.scal[1];
      const float kn    = sh.m.scal[2];
      const int   sgrp  = lane >> 4;   // slot-in-group 0..3
      const int   c4    = lane & 15;   // float4 index within slot
      const float4 kk  = reinterpret_cast<const float4*>(sh.m.key)[c4];
      const float4 kp4 = reinterpret_cast<const float4*>(sh.m.kp)[c4];
      float Zp = 0.f, S2p = 0.f;
      float4 acc4 = make_float4(0.f,0.f,0.f,0.f);
      float* memp = P.mem + ((size_t)b*2048 + chunk*512) * 64;
      const float* ebp = P.ebuf + pp*131072 + b*2048 + chunk*512;
      float*       ebc = P.ebuf + p *131072 + b*2048 + chunk*512;

      for (int it = 0; it < 16; ++it) {
        const int n = it*32 + wv*4 + sgrp;            // slot within 512-chunk
        float4 m4 = reinterpret_cast<const float4*>(memp + (size_t)n*64)[c4];
        if (t > 0) {
          // apply pending rank-1 update from step t-1, write back
          const float wp = ebp[n] * invZp;
          m4.x = fmaf(wp, kp4.x, m4.x);
          m4.y = fmaf(wp, kp4.y, m4.y);
          m4.z = fmaf(wp, kp4.z, m4.z);
          m4.w = fmaf(wp, kp4.w, m4.w);
          reinterpret_cast<float4*>(memp + (size_t)n*64)[c4] = m4;
        }
        float num = m4.x*kk.x + m4.y*kk.y + m4.z*kk.z + m4.w*kk.w;
        float ssq = m4.x*m4.x + m4.y*m4.y + m4.z*m4.z + m4.w*m4.w;
        #pragma unroll
        for (int off = 1; off < 16; off <<= 1) {
          num += __shfl_xor(num, off);
          ssq += __shfl_xor(ssq, off);
        }
        const float sim = num / (fmaxf(sqrtf(ssq), EPSF) * kn);
        const float e = __expf(beta * sim);
        if (c4 == 0) { ebc[n] = e; Zp += e; S2p += e*e; }
        acc4.x = fmaf(e, m4.x, acc4.x);
        acc4.y = fmaf(e, m4.y, acc4.y);
        acc4.z = fmaf(e, m4.z, acc4.z);
        acc4.w = fmaf(e, m4.w, acc4.w);
      }
      // Z / S2 reduce + atomics
      #pragma unroll
      for (int off = 32; off; off >>= 1) { Zp += __shfl_down(Zp, off); S2p += __shfl_down(S2p, off); }
      if (lane == 0) { atomicAdd(P.Zb + p*64 + b, Zp); atomicAdd(P.S2b + p*64 + b, S2p); }
      // acc reduce across slot groups -> lanes 0..15
      #pragma unroll
      for (int off = 16; off < 64; off <<= 1) {
        acc4.x += __shfl_down(acc4.x, off); acc4.y += __shfl_down(acc4.y, off);
        acc4.z += __shfl_down(acc4.z, off); acc4.w += __shfl_down(acc4.w, off);
      }
      if (lane < 16) reinterpret_cast<float4*>(&sh.m.red[wv][0])[lane] = acc4;
      __syncthreads();
      if (tid < 64) {
        float s = 0.f;
        #pragma unroll
        for (int qq = 0; qq < 8; ++qq) s += sh.m.red[qq][c];
        atomicAdd(P.AccT + p*4096 + c*64 + b, s);
      }
      __syncthreads();
      // y slice: outs [chunk*64, +64) for batch b
      {
        const int oc = chunk*64 + c;
        float py = 0.f;
        #pragma unroll 4
        for (int jj = wv*64; jj < wv*64 + 64; ++jj)
          py = fmaf(hp[jj*64 + b], P.W_out[jj*256 + oc], py);
        sh.m.red[wv][c] = py;
      }
      __syncthreads();
      if (tid < 64) {
        const int oc = chunk*64 + c;
        float s = P.b_out[oc];
        #pragma unroll
        for (int qq = 0; qq < 8; ++qq) s += sh.m.red[qq][c];
        P.out[((size_t)t*64 + b)*256 + oc] = s;
      }
      // gen + supervised loss (chunk-0 blocks only)
      if (chunk == 0) {
        __syncthreads();
        float pg = 0.f;
        #pragma unroll 4
        for (int jj = wv*64; jj < wv*64 + 64; ++jj)
          pg = fmaf(hp[jj*64 + b], P.W_gen[jj*64 + c], pg);
        sh.m.red[wv][c] = pg;
        __syncthreads();
        if (tid < 64) {
          float gv = P.b_gen[c];
          #pragma unroll
          for (int qq = 0; qq < 8; ++qq) gv += sh.m.red[qq][c];
          float d = sh.m.key[c] - gv;
          float s = d * d;
          #pragma unroll
          for (int off = 32; off; off >>= 1) s += __shfl_down(s, off);
          if (c == 0) atomicAdd(P.loss, s * (1.f/4096.f));
        }
      }
    }
    grid.sync();
  }
  if (bid == 0 && tid == 0) P.out[8388608] = *P.loss;
}

// xs (T,B,IN) -> xT (T,IN,B) stored in d_out (y overwrites it step-by-step later)
__global__ void transpose_x(const float* __restrict__ xs, float* __restrict__ xT) {
  const int t = blockIdx.x >> 2, tile = blockIdx.x & 3;
  __shared__ float tl[64][65];
  const int i = threadIdx.x & 63, r0 = threadIdx.x >> 6;
  for (int bb = r0; bb < 64; bb += 4)
    tl[bb][i] = xs[((size_t)t*64 + bb)*256 + tile*64 + i];
  __syncthreads();
  for (int ii = r0; ii < 64; ii += 4)
    xT[(size_t)t*16384 + (size_t)(tile*64 + ii)*64 + i] = tl[i][ii];
}

// build interleaved recurrent weights: rows [0,256)=W_ih(x), [256,768)=W_hh, [768,832)=read-head-folded W_ih
__global__ void build_wrec(const float* __restrict__ W_ih, const float* __restrict__ W_hh,
                           float* __restrict__ Wrec2) {
  const int id = blockIdx.x * 256 + threadIdx.x;   // over 832*2048
  if (id >= 832*2048) return;
  const int row = id >> 11, col = id & 2047;
  float v;
  if (row < 256)      v = W_ih[(size_t)row*2048 + col];
  else if (row < 768) v = W_hh[(size_t)(row-256)*2048 + col];
  else {
    const int cc = row - 768;
    const float* p0 = W_ih + (size_t)(256 + cc*4)*2048 + col;
    v = p0[0] + p0[2048] + p0[2*2048] + p0[3*2048];
  }
  const int g = col >> 9, j = col & 511;
  const int blk = j >> 1, jl = j & 1;
  Wrec2[((size_t)blk*832 + row)*8 + (jl*4 + g)] = v;
}

extern "C" void kernel_launch(void* const* d_in, const int* in_sizes, int n_in,
                              void* d_out, int out_size, void* d_ws, size_t ws_size,
                              hipStream_t stream) {
  const float* xs     = (const float*)d_in[0];
  const float* W_ih   = (const float*)d_in[1];
  const float* W_hh   = (const float*)d_in[2];
  const float* b_lstm = (const float*)d_in[3];
  const float* W_out  = (const float*)d_in[4];
  const float* b_out  = (const float*)d_in[5];
  const float* W_key  = (const float*)d_in[6];
  const float* b_key  = (const float*)d_in[7];
  const float* W_beta = (const float*)d_in[8];
  const float* b_beta = (const float*)d_in[9];
  const float* W_gen  = (const float*)d_in[10];
  const float* b_gen  = (const float*)d_in[11];
  float* out = (float*)d_out;

  float* ws = (float*)d_ws;
  float* mem   = ws;               // 8,388,608
  float* Wrec2 = mem   + 8388608;  // 1,703,936
  float* hT    = Wrec2 + 1703936;  // 65,536
  float* cT    = hT    + 65536;    // 32,768
  float* ebuf  = cT    + 32768;    // 262,144
  float* keybT = ebuf  + 262144;   // 8,192
  float* AccT  = keybT + 8192;     // 8,192
  float* Zb    = AccT  + 8192;     // 128
  float* S2b   = Zb    + 128;      // 128
  float* lossp = S2b   + 128;      // 1
  const size_t ws_floats = 10469633;

  hipMemsetAsync(d_ws, 0, ws_floats * sizeof(float), stream);
  transpose_x<<<dim3(2048), dim3(256), 0, stream>>>(xs, out);
  build_wrec<<<dim3(6656), dim3(256), 0, stream>>>(W_ih, W_hh, Wrec2);

  Params prm;
  prm.Wrec2 = Wrec2;  prm.b_lstm = b_lstm;
  prm.W_out = W_out;  prm.b_out = b_out;
  prm.W_key = W_key;  prm.b_key = b_key;
  prm.W_beta = W_beta; prm.b_beta = b_beta;
  prm.W_gen = W_gen;  prm.b_gen = b_gen;
  prm.mem = mem; prm.hT = hT; prm.cT = cT; prm.ebuf = ebuf;
  prm.keybT = keybT; prm.AccT = AccT; prm.Zb = Zb; prm.S2b = S2b;
  prm.loss = lossp; prm.out = out;

  void* kargs[] = { &prm };
  hipLaunchCooperativeKernel(reinterpret_cast<void*>(&dnc_main),
                             dim3(256), dim3(512), kargs, 0, stream);
}

// Round 2
// 55935.840 us; speedup vs baseline: 1.1177x; 1.1177x over previous
//
#include <hip/hip_runtime.h>

#define EPSF 1e-8f

// T=512 B=64 IN=256 OUT=256 H=512 N=2048 C=64 R=4
// One block per batch, 1024 threads, ZERO grid syncs (all state block-local).
// Recurrent input rows: [x(256) | h(512) | r(64 folded over R=4 heads)] = 832.

struct P2 {
  const float* W2;      // [832][2048] fused recurrent weights
  const float* b_lstm;  // 2048
  const float* W_out;   // [512][256]
  const float* b_out;   // 256
  const float* W_key;   // [512][64]
  const float* b_key;   // 64
  const float* W_beta;  // 512
  const float* b_beta;  // 1
  const float* W_gen;   // [512][64]
  const float* b_gen;   // 64
  const float* xs;      // [512][64][256]
  float* mem;           // [64][2048][64]
  float* out;           // [512][64][256] y, + loss at 8388608
};

__device__ __forceinline__ float sigm(float x) { return 1.f / (1.f + __expf(-x)); }

__global__ void __launch_bounds__(1024, 4) dnc_batch(P2 P) {
  const int tid  = threadIdx.x;
  const int b    = blockIdx.x;
  const int lane = tid & 63;
  const int wv   = tid >> 6;     // 0..15

  __shared__ float s_inp[832];       // [x | h | r]  (h persists across steps)
  __shared__ float s_c[512];
  __shared__ float s_gates[2048];
  __shared__ float s_part[4][2048];  // 32 KB reduction scratch (GEMV/proj/mem)
  __shared__ float s_ebuf[2][2048];  // exp(beta*sim) double buffer
  __shared__ float s_key[64], s_kprev[64], s_genv[64], s_accv[64];
  __shared__ float s_wred[32];
  __shared__ float s_scal[4];        // 0:invZ_prev 1:S2_prev 2:beta 3:||key||

  float* memp = P.mem + (size_t)b * 131072;
  float lossacc = 0.f;

  // zero own mem chunk (ws is poisoned 0xAA) + init LDS state
  {
    float4 z4 = make_float4(0.f, 0.f, 0.f, 0.f);
    float4* m4p = (float4*)memp;
    for (int i = tid; i < 32768; i += 1024) m4p[i] = z4;
    if (tid < 512) s_c[tid] = 0.f;
    for (int i = 256 + tid; i < 832; i += 1024) s_inp[i] = 0.f;
  }
  __syncthreads();

  for (int t = 0; t < 512; ++t) {
    const int p = t & 1, pp = p ^ 1;

    // ---- phase 1: load x_t, finalize r_{t-1} = invZ*(Acc + S2*invZ*key_prev)
    if (tid < 256) {
      s_inp[tid] = P.xs[((size_t)t * 64 + b) * 256 + tid];
    } else if (tid < 320) {
      const int c = tid - 256;
      float r = 0.f;
      if (t > 0) {
        const float invZ = s_scal[0], S2 = s_scal[1];
        r = invZ * (s_accv[c] + S2 * invZ * s_kprev[c]);
      }
      s_inp[768 + c] = r;
    }
    __syncthreads();

    // ---- phase 2: gates GEMV partials (4 row-chunks x 256 col-groups x 8 cols)
    {
      const int q = tid >> 8, cg = tid & 255, c0 = cg << 3;
      const int r0 = q * 208;
      float4 aA = make_float4(0.f, 0.f, 0.f, 0.f);
      float4 aB = make_float4(0.f, 0.f, 0.f, 0.f);
      const float* wbase = P.W2 + (size_t)r0 * 2048 + c0;
      #pragma unroll 4
      for (int r = 0; r < 208; ++r) {
        const float v = s_inp[r0 + r];
        const float4 wA = *(const float4*)(wbase + (size_t)r * 2048);
        const float4 wB = *(const float4*)(wbase + (size_t)r * 2048 + 4);
        aA.x = fmaf(v, wA.x, aA.x); aA.y = fmaf(v, wA.y, aA.y);
        aA.z = fmaf(v, wA.z, aA.z); aA.w = fmaf(v, wA.w, aA.w);
        aB.x = fmaf(v, wB.x, aB.x); aB.y = fmaf(v, wB.y, aB.y);
        aB.z = fmaf(v, wB.z, aB.z); aB.w = fmaf(v, wB.w, aB.w);
      }
      *(float4*)&s_part[q][c0]     = aA;
      *(float4*)&s_part[q][c0 + 4] = aB;
    }
    __syncthreads();
    // ---- 2b: reduce partials -> gates
    {
      const int c1 = tid, c2 = tid + 1024;
      s_gates[c1] = s_part[0][c1] + s_part[1][c1] + s_part[2][c1] + s_part[3][c1];
      s_gates[c2] = s_part[0][c2] + s_part[1][c2] + s_part[2][c2] + s_part[3][c2];
    }
    __syncthreads();

    // ---- phase 3: LSTM cell update -> h into s_inp[256+j]
    if (tid < 512) {
      const int j = tid;
      const float gi = s_gates[j]        + P.b_lstm[j];
      const float gf = s_gates[512 + j]  + P.b_lstm[512 + j];
      const float gg = s_gates[1024 + j] + P.b_lstm[1024 + j];
      const float go = s_gates[1536 + j] + P.b_lstm[1536 + j];
      const float cn = sigm(gf) * s_c[j] + sigm(gi) * tanhf(gg);
      s_c[j] = cn;
      s_inp[256 + j] = sigm(go) * tanhf(cn);
    }
    __syncthreads();

    // ---- phase 4a: y = h @ W_out + b_out
    {
      const int q = tid >> 8, col = tid & 255, r0 = q * 128;
      const float* hb = s_inp + 256;
      const float* wp = P.W_out + (size_t)r0 * 256 + col;
      float a = 0.f;
      #pragma unroll 4
      for (int r = 0; r < 128; ++r) a = fmaf(hb[r0 + r], wp[(size_t)r * 256], a);
      s_part[q][col] = a;
    }
    __syncthreads();
    if (tid < 256) {
      const float yv = P.b_out[tid] + s_part[0][tid] + s_part[1][tid]
                     + s_part[2][tid] + s_part[3][tid];
      P.out[((size_t)t * 64 + b) * 256 + tid] = yv;
    }
    __syncthreads();

    // ---- phase 4b: key / gen projections (8 row-chunks x 128 cols)
    {
      const int qk = tid >> 7, cl = tid & 127, r0 = qk * 64;
      const float* hb = s_inp + 256;
      const float* wp = (cl < 64) ? (P.W_key + cl) : (P.W_gen + (cl - 64));
      float a = 0.f;
      #pragma unroll 4
      for (int r = 0; r < 64; ++r) a = fmaf(hb[r0 + r], wp[(size_t)(r0 + r) * 64], a);
      ((float*)s_part)[qk * 128 + cl] = a;
    }
    __syncthreads();
    if (tid < 128) {
      const float* fp = (const float*)s_part;
      float v = fp[tid] + fp[128 + tid] + fp[256 + tid] + fp[384 + tid]
              + fp[512 + tid] + fp[640 + tid] + fp[768 + tid] + fp[896 + tid];
      if (tid < 64) s_key[tid]       = v + P.b_key[tid];
      else          s_genv[tid - 64] = v + P.b_gen[tid - 64];
    }
    __syncthreads();

    // ---- phase 4c: beta (waves 0-7), ||key|| (wave 8), loss (wave 9)
    if (tid < 512) {
      float pb = s_inp[256 + tid] * P.W_beta[tid];
      #pragma unroll
      for (int off = 32; off; off >>= 1) pb += __shfl_down(pb, off);
      if (lane == 0) s_wred[wv] = pb;
    } else if (wv == 8) {
      const float kv = s_key[lane];
      float sq = kv * kv;
      #pragma unroll
      for (int off = 32; off; off >>= 1) sq += __shfl_down(sq, off);
      if (lane == 0) s_scal[3] = fmaxf(sqrtf(sq), EPSF);
    } else if (wv == 9) {
      const float d = s_key[lane] - s_genv[lane];
      float ds = d * d;
      #pragma unroll
      for (int off = 32; off; off >>= 1) ds += __shfl_down(ds, off);
      if (lane == 0) lossacc += ds;
    }
    __syncthreads();
    if (tid == 0) {
      float s = P.b_beta[0];
      #pragma unroll
      for (int k = 0; k < 8; ++k) s += s_wred[k];
      s_scal[2] = (s > 20.f) ? s : log1pf(__expf(s));  // softplus
    }
    __syncthreads();

    // ---- phase 5: fused memory pass (apply pending update, sim, exp, acc)
    {
      const int sgrp = lane >> 4, c4 = lane & 15;
      const float beta = s_scal[2], kn = s_scal[3], invZp = s_scal[0];
      const float4 kk  = ((const float4*)s_key)[c4];
      const float4 kp4 = ((const float4*)s_kprev)[c4];
      float Zp = 0.f, S2p = 0.f;
      float4 acc4 = make_float4(0.f, 0.f, 0.f, 0.f);
      for (int it = 0; it < 32; ++it) {
        const int n = it * 64 + wv * 4 + sgrp;
        float4 m4 = ((const float4*)(memp + (size_t)n * 64))[c4];
        if (t > 0) {
          const float wpv = s_ebuf[pp][n] * invZp;   // pending w_{t-1}[n]
          m4.x = fmaf(wpv, kp4.x, m4.x); m4.y = fmaf(wpv, kp4.y, m4.y);
          m4.z = fmaf(wpv, kp4.z, m4.z); m4.w = fmaf(wpv, kp4.w, m4.w);
          ((float4*)(memp + (size_t)n * 64))[c4] = m4;
        }
        float num = m4.x * kk.x + m4.y * kk.y + m4.z * kk.z + m4.w * kk.w;
        float ssq = m4.x * m4.x + m4.y * m4.y + m4.z * m4.z + m4.w * m4.w;
        #pragma unroll
        for (int off = 1; off < 16; off <<= 1) {
          num += __shfl_xor(num, off);
          ssq += __shfl_xor(ssq, off);
        }
        const float sim = num / (fmaxf(sqrtf(ssq), EPSF) * kn);
        const float e = __expf(beta * sim);
        if (c4 == 0) { s_ebuf[p][n] = e; Zp += e; S2p += e * e; }
        acc4.x = fmaf(e, m4.x, acc4.x); acc4.y = fmaf(e, m4.y, acc4.y);
        acc4.z = fmaf(e, m4.z, acc4.z); acc4.w = fmaf(e, m4.w, acc4.w);
      }
      #pragma unroll
      for (int off = 32; off; off >>= 1) {
        Zp  += __shfl_down(Zp, off);
        S2p += __shfl_down(S2p, off);
      }
      if (lane == 0) { s_wred[wv] = Zp; s_wred[16 + wv] = S2p; }
      #pragma unroll
      for (int off = 16; off < 64; off <<= 1) {
        acc4.x += __shfl_down(acc4.x, off); acc4.y += __shfl_down(acc4.y, off);
        acc4.z += __shfl_down(acc4.z, off); acc4.w += __shfl_down(acc4.w, off);
      }
      if (lane < 16) ((float4*)s_part)[wv * 16 + lane] = acc4;
    }
    __syncthreads();
    // ---- phase 6: finalize Acc/Z/S2, key_prev <- key
    if (tid < 64) {
      const float* fp = (const float*)s_part;
      float a = 0.f;
      #pragma unroll
      for (int w = 0; w < 16; ++w) a += fp[w * 64 + tid];
      s_accv[tid]  = a;
      s_kprev[tid] = s_key[tid];
    } else if (tid == 64) {
      float Z = 0.f, S2 = 0.f;
      #pragma unroll
      for (int k = 0; k < 16; ++k) { Z += s_wred[k]; S2 += s_wred[16 + k]; }
      s_scal[0] = 1.f / Z;
      s_scal[1] = S2;
    }
    __syncthreads();
  }

  if (tid == 576) atomicAdd(P.out + 8388608, lossacc * (1.f / 4096.f));
}

// Build fused recurrent weights W2[832][2048]:
// rows [0,256)=W_ih(x-part), [256,768)=W_hh, [768,832)=W_ih read-rows folded over R=4
__global__ void build_wrec(const float* __restrict__ W_ih, const float* __restrict__ W_hh,
                           float* __restrict__ W2) {
  const int id = blockIdx.x * 256 + threadIdx.x;  // over 832*2048
  if (id >= 832 * 2048) return;
  const int row = id >> 11, col = id & 2047;
  float v;
  if (row < 256)      v = W_ih[(size_t)row * 2048 + col];
  else if (row < 768) v = W_hh[(size_t)(row - 256) * 2048 + col];
  else {
    const int cc = row - 768;
    const float* p0 = W_ih + (size_t)(256 + cc * 4) * 2048 + col;
    v = p0[0] + p0[2048] + p0[2 * 2048] + p0[3 * 2048];
  }
  W2[(size_t)row * 2048 + col] = v;
}

extern "C" void kernel_launch(void* const* d_in, const int* in_sizes, int n_in,
                              void* d_out, int out_size, void* d_ws, size_t ws_size,
                              hipStream_t stream) {
  const float* xs     = (const float*)d_in[0];
  const float* W_ih   = (const float*)d_in[1];
  const float* W_hh   = (const float*)d_in[2];
  const float* b_lstm = (const float*)d_in[3];
  const float* W_out  = (const float*)d_in[4];
  const float* b_out  = (const float*)d_in[5];
  const float* W_key  = (const float*)d_in[6];
  const float* b_key  = (const float*)d_in[7];
  const float* W_beta = (const float*)d_in[8];
  const float* b_beta = (const float*)d_in[9];
  const float* W_gen  = (const float*)d_in[10];
  const float* b_gen  = (const float*)d_in[11];
  float* out = (float*)d_out;

  float* ws  = (float*)d_ws;
  float* mem = ws;              // 8,388,608 floats (64 x 2048 x 64)
  float* W2  = mem + 8388608;   // 1,703,936 floats (832 x 2048)

  // loss accumulator slot must start at 0 each call
  hipMemsetAsync(out + 8388608, 0, sizeof(float), stream);

  build_wrec<<<dim3(6656), dim3(256), 0, stream>>>(W_ih, W_hh, W2);

  P2 prm;
  prm.W2 = W2;        prm.b_lstm = b_lstm;
  prm.W_out = W_out;  prm.b_out = b_out;
  prm.W_key = W_key;  prm.b_key = b_key;
  prm.W_beta = W_beta; prm.b_beta = b_beta;
  prm.W_gen = W_gen;  prm.b_gen = b_gen;
  prm.xs = xs;        prm.mem = mem;  prm.out = out;

  dnc_batch<<<dim3(64), dim3(1024), 0, stream>>>(prm);
}

// Round 3
// 18107.568 us; speedup vs baseline: 3.4526x; 3.0891x over previous
//
#include <hip/hip_runtime.h>

#define EPSF 1e-8f

// T=512 B=64 IN=256 OUT=256 H=512 N=2048 C=64 R=4
// 256 blocks x 1024 threads (1 block/CU), 4 blocks per batch.
// mem[batch][2048][64] lives entirely in REGISTERS: each block owns 512 slots,
// each thread 8 slots' float4 slices (32 VGPR). Zero global traffic for mem.
// Cross-block (within-batch) sync: per-batch monotone atomic counter barriers.

struct P3 {
  const float* W2p;     // [4][832][512] per-chunk interleaved recurrent weights
  const float* b_lstm;  // 2048
  const float* W_out;   // [512][256]
  const float* b_out;   // 256
  const float* W_key;   // [512][64]
  const float* b_key;   // 64
  const float* W_beta;  // 512
  const float* b_beta;  // 1
  const float* W_gen;   // [512][64]
  const float* b_gen;   // 64
  const float* xs;      // [512][64][256]
  float* hbuf;          // [64][512]
  float* AccP;          // [64][4][64]
  float* ZP;            // [64][4]
  float* S2P;           // [64][4]
  unsigned* ctr;        // [64][16]  (64B-strided per-batch counters)
  float* out;           // [512][64][256] + loss at 8388608
};

__device__ __forceinline__ float sigm(float x) { return 1.f / (1.f + __expf(-x)); }

__device__ __forceinline__ void bar_post(unsigned* c) {
  // release: drains this XCD's dirty L2 so peers (other XCDs) can see our data
  __hip_atomic_fetch_add(c, 1u, __ATOMIC_RELEASE, __HIP_MEMORY_SCOPE_AGENT);
}
__device__ __forceinline__ void bar_wait(unsigned* c, unsigned target) {
  // relaxed agent loads bypass local L1/L2 -> always see remote atomics
  while (__hip_atomic_load(c, __ATOMIC_RELAXED, __HIP_MEMORY_SCOPE_AGENT) < target)
    __builtin_amdgcn_s_sleep(2);
  __builtin_amdgcn_fence(__ATOMIC_ACQUIRE, "agent");  // invalidate L1+L2 for data reads
}

__global__ void __launch_bounds__(1024, 4) dnc_b4(P3 P) {
  const int tid   = threadIdx.x;
  const int bid   = blockIdx.x;
  // swizzle: XCD (= bid%8, heuristic) hosts a single chunk value
  const int chunk = (bid >> 1) & 3;
  const int b     = ((bid >> 3) << 1) | (bid & 1);
  const int lane  = tid & 63;
  const int wv    = tid >> 6;      // 0..15
  const int sgrp  = lane >> 4;     // 0..3
  const int c4    = lane & 15;

  __shared__ float s_inp[832];     // [x(256) | h(512) | r(64)]
  __shared__ float s_gates[512];   // own 128 j x 4 gates (cc = jl*4+g)
  __shared__ float s_c[128];
  __shared__ float s_part[4096];   // reduction scratch
  __shared__ float s_e[512];       // exp(beta*sim) for own slots (pending buffer)
  __shared__ float s_key[64];
  __shared__ float s_kprev[64];
  __shared__ float s_genv[64];
  __shared__ float s_wred[32];
  __shared__ float s_scal[4];      // 0:invZ_prev 1:S2_prev 2:beta 3:||key||

  unsigned* ctr = P.ctr + b * 16;
  float* hb = P.hbuf + b * 512;

  float4 mreg[8];                  // own 512 slots: subgroup slot n, lane c4 holds floats [c4*4..+4)
#pragma unroll
  for (int i = 0; i < 8; ++i) mreg[i] = make_float4(0.f, 0.f, 0.f, 0.f);

  for (int i = 256 + tid; i < 832; i += 1024) s_inp[i] = 0.f;  // h=r=0
  if (tid < 128) s_c[tid] = 0.f;
  float lossacc = 0.f;
  __syncthreads();

  for (int t = 0; t < 512; ++t) {
    //================ phase A: wait B_{t-1}; x load; r finalize ================
    float xv = 0.f;
    if (tid < 256) xv = P.xs[((size_t)t * 64 + b) * 256 + tid];  // prefetch (const input)
    if (t > 0 && tid == 0) bar_wait(ctr, 8u * (unsigned)t);
    __syncthreads();
    if (tid < 256) s_inp[tid] = xv;
    float accT = 0.f;
    if (t > 0) {
      if (tid < 64) {
        const float* ap = P.AccP + b * 256 + tid;
        accT = ap[0] + ap[64] + ap[128] + ap[192];
      } else if (tid == 64) {
        const float* zp = P.ZP + b * 4;
        const float* sp = P.S2P + b * 4;
        const float Z  = zp[0] + zp[1] + zp[2] + zp[3];
        const float S2 = sp[0] + sp[1] + sp[2] + sp[3];
        s_scal[0] = 1.f / Z;
        s_scal[1] = S2;
      }
    } else if (tid == 64) {
      s_scal[0] = 0.f; s_scal[1] = 0.f;
    }
    __syncthreads();
    if (tid < 64) {
      float r = 0.f;
      if (t > 0) {
        const float iZ = s_scal[0];
        r = iZ * (accT + s_scal[1] * iZ * s_kprev[tid]);
      }
      s_inp[768 + tid] = r;
    }
    __syncthreads();

    //================ phase B: GEMV (own 512 gate-cols) -> LSTM -> publish h ===
    {
      const int q = tid >> 7, cg = tid & 127;          // 8 row-chunks x 128 col-groups
      const float* wp = P.W2p + (size_t)chunk * 425984 + (size_t)(q * 104) * 512 + (cg << 2);
      const float* ip = s_inp + q * 104;
      float4 a4 = make_float4(0.f, 0.f, 0.f, 0.f);
#pragma unroll 4
      for (int r = 0; r < 104; ++r) {
        const float v = ip[r];
        const float4 w4 = *(const float4*)(wp + (size_t)r * 512);
        a4.x = fmaf(v, w4.x, a4.x); a4.y = fmaf(v, w4.y, a4.y);
        a4.z = fmaf(v, w4.z, a4.z); a4.w = fmaf(v, w4.w, a4.w);
      }
      *(float4*)&s_part[q * 512 + (cg << 2)] = a4;
    }
    __syncthreads();
    if (tid < 512) {
      s_gates[tid] = s_part[tid]        + s_part[512 + tid]  + s_part[1024 + tid] + s_part[1536 + tid]
                   + s_part[2048 + tid] + s_part[2560 + tid] + s_part[3072 + tid] + s_part[3584 + tid];
    }
    __syncthreads();
    if (tid < 128) {
      const int jl = tid, cb = chunk * 128 + jl;
      const float gi = s_gates[jl * 4 + 0] + P.b_lstm[cb];
      const float gf = s_gates[jl * 4 + 1] + P.b_lstm[512 + cb];
      const float gg = s_gates[jl * 4 + 2] + P.b_lstm[1024 + cb];
      const float go = s_gates[jl * 4 + 3] + P.b_lstm[1536 + cb];
      const float cn = sigm(gf) * s_c[jl] + sigm(gi) * tanhf(gg);
      s_c[jl] = cn;
      const float hn = sigm(go) * tanhf(cn);
      s_inp[256 + cb] = hn;
      hb[cb] = hn;                                   // publish own h chunk
    }
    // barrier A
    __syncthreads();
    if (tid == 0) { bar_post(ctr); bar_wait(ctr, 8u * (unsigned)t + 4u); }
    __syncthreads();

    //================ phase C: full h; projections; beta/||key||/loss ==========
    if (tid < 384) {                                  // load peers' h chunks
      const int pi = tid >> 7;
      const int pc = (chunk + 1 + pi) & 3;
      const int jl = tid & 127;
      s_inp[256 + pc * 128 + jl] = hb[pc * 128 + jl];
    }
    __syncthreads();
    {
      const float* h = s_inp + 256;
      {  // key | gen partials: 8 row-chunks x 128 cols
        const int rc = tid >> 7, cl = tid & 127;
        const float* wp = (cl < 64) ? (P.W_key + cl) : (P.W_gen + (cl - 64));
        float a = 0.f;
#pragma unroll 4
        for (int r = rc * 64; r < rc * 64 + 64; ++r) a = fmaf(h[r], wp[(size_t)r * 64], a);
        s_part[rc * 128 + cl] = a;
      }
      {  // y partials (own 64-col slice): 16 row-chunks x 64 cols
        const int rc = tid >> 6, col = tid & 63;
        const float* wp = P.W_out + chunk * 64 + col;
        float a = 0.f;
#pragma unroll 4
        for (int r = rc * 32; r < rc * 32 + 32; ++r) a = fmaf(h[r], wp[(size_t)r * 256], a);
        s_part[1024 + rc * 64 + col] = a;
      }
      {  // beta partials
        float pb = (tid < 512) ? h[tid] * P.W_beta[tid] : 0.f;
#pragma unroll
        for (int off = 32; off; off >>= 1) pb += __shfl_down(pb, off);
        if (tid < 512 && lane == 0) s_wred[wv] = pb;
      }
    }
    __syncthreads();
    if (tid < 64) {
      float v = 0.f;
#pragma unroll
      for (int k = 0; k < 8; ++k) v += s_part[k * 128 + tid];
      s_key[tid] = v + P.b_key[tid];
    } else if (tid < 128) {
      const int c = tid - 64;
      float v = 0.f;
#pragma unroll
      for (int k = 0; k < 8; ++k) v += s_part[k * 128 + 64 + c];
      s_genv[c] = v + P.b_gen[c];
    } else if (tid < 192) {
      const int col = tid - 128;
      float v = 0.f;
#pragma unroll
      for (int k = 0; k < 16; ++k) v += s_part[1024 + k * 64 + col];
      P.out[((size_t)t * 64 + b) * 256 + chunk * 64 + col] = v + P.b_out[chunk * 64 + col];
    } else if (tid == 192) {
      float s = P.b_beta[0];
#pragma unroll
      for (int k = 0; k < 8; ++k) s += s_wred[k];
      s_scal[2] = (s > 20.f) ? s : log1pf(__expf(s));  // softplus
    }
    __syncthreads();
    if (wv == 0) {
      const float kv = s_key[lane];
      float sq = kv * kv;
#pragma unroll
      for (int off = 32; off; off >>= 1) sq += __shfl_down(sq, off);
      if (lane == 0) s_scal[3] = fmaxf(sqrtf(sq), EPSF);
    } else if (wv == 1 && chunk == 0) {
      const float d = s_key[lane] - s_genv[lane];
      float ds = d * d;
#pragma unroll
      for (int off = 32; off; off >>= 1) ds += __shfl_down(ds, off);
      if (lane == 0) lossacc += ds;                   // tid 64 accumulates
    }
    __syncthreads();

    //================ phase D: register mem pass (pending update + sim + acc) ==
    {
      const float beta = s_scal[2], kn = s_scal[3], invZp = s_scal[0];
      const float4 kk  = ((const float4*)s_key)[c4];
      const float4 kp4 = ((const float4*)s_kprev)[c4];
      float Zp = 0.f, S2p = 0.f;
      float4 acc4 = make_float4(0.f, 0.f, 0.f, 0.f);
      const int nbase = (wv * 4 + sgrp) * 8;
#pragma unroll
      for (int it = 0; it < 8; ++it) {
        float4 m4 = mreg[it];
        if (t > 0) {
          const float wpv = s_e[nbase + it] * invZp;  // w_{t-1}[n]
          m4.x = fmaf(wpv, kp4.x, m4.x); m4.y = fmaf(wpv, kp4.y, m4.y);
          m4.z = fmaf(wpv, kp4.z, m4.z); m4.w = fmaf(wpv, kp4.w, m4.w);
        }
        float num = m4.x * kk.x + m4.y * kk.y + m4.z * kk.z + m4.w * kk.w;
        float ssq = m4.x * m4.x + m4.y * m4.y + m4.z * m4.z + m4.w * m4.w;
#pragma unroll
        for (int off = 1; off < 16; off <<= 1) {
          num += __shfl_xor(num, off);
          ssq += __shfl_xor(ssq, off);
        }
        const float sim = num / (fmaxf(sqrtf(ssq), EPSF) * kn);
        const float e = __expf(beta * sim);
        if (c4 == 0) { s_e[nbase + it] = e; Zp += e; S2p += e * e; }
        acc4.x = fmaf(e, m4.x, acc4.x); acc4.y = fmaf(e, m4.y, acc4.y);
        acc4.z = fmaf(e, m4.z, acc4.z); acc4.w = fmaf(e, m4.w, acc4.w);
        mreg[it] = m4;
      }
#pragma unroll
      for (int off = 32; off; off >>= 1) {
        Zp += __shfl_down(Zp, off); S2p += __shfl_down(S2p, off);
      }
#pragma unroll
      for (int off = 16; off < 64; off <<= 1) {
        acc4.x += __shfl_down(acc4.x, off); acc4.y += __shfl_down(acc4.y, off);
        acc4.z += __shfl_down(acc4.z, off); acc4.w += __shfl_down(acc4.w, off);
      }
      if (lane < 16) ((float4*)s_part)[wv * 16 + lane] = acc4;
      if (lane == 0) { s_wred[wv] = Zp; s_wred[16 + wv] = S2p; }
    }
    __syncthreads();
    if (tid < 64) {
      float a = 0.f;
#pragma unroll
      for (int w = 0; w < 16; ++w) a += s_part[w * 64 + tid];
      P.AccP[(b * 4 + chunk) * 64 + tid] = a;         // publish Acc partial
      s_kprev[tid] = s_key[tid];
    } else if (tid == 64) {
      float Z = 0.f, S2 = 0.f;
#pragma unroll
      for (int k = 0; k < 16; ++k) { Z += s_wred[k]; S2 += s_wred[16 + k]; }
      P.ZP[b * 4 + chunk] = Z;
      P.S2P[b * 4 + chunk] = S2;
    }
    // barrier B (post only; wait happens at next step's phase A)
    __syncthreads();
    if (tid == 0) bar_post(ctr);
  }

  if (chunk == 0 && tid == 64) atomicAdd(P.out + 8388608, lossacc * (1.f / 4096.f));
}

// W2p[chunk][832][512]: cc = jl*4+g <-> original col g*512 + chunk*128 + jl.
// rows [0,256)=W_ih(x), [256,768)=W_hh, [768,832)=W_ih read-rows folded over R=4.
__global__ void build_w2p(const float* __restrict__ W_ih, const float* __restrict__ W_hh,
                          float* __restrict__ W2p) {
  const int id = blockIdx.x * 256 + threadIdx.x;
  if (id >= 4 * 832 * 512) return;
  const int chunk = id / 425984;
  const int rem   = id % 425984;
  const int row   = rem >> 9;
  const int cc    = rem & 511;
  const int jl = cc >> 2, g = cc & 3;
  const int col = g * 512 + chunk * 128 + jl;
  float v;
  if (row < 256)      v = W_ih[(size_t)row * 2048 + col];
  else if (row < 768) v = W_hh[(size_t)(row - 256) * 2048 + col];
  else {
    const int c2 = row - 768;
    const float* p0 = W_ih + (size_t)(256 + c2 * 4) * 2048 + col;
    v = p0[0] + p0[2048] + p0[4096] + p0[6144];
  }
  W2p[id] = v;
}

extern "C" void kernel_launch(void* const* d_in, const int* in_sizes, int n_in,
                              void* d_out, int out_size, void* d_ws, size_t ws_size,
                              hipStream_t stream) {
  const float* xs     = (const float*)d_in[0];
  const float* W_ih   = (const float*)d_in[1];
  const float* W_hh   = (const float*)d_in[2];
  const float* b_lstm = (const float*)d_in[3];
  const float* W_out  = (const float*)d_in[4];
  const float* b_out  = (const float*)d_in[5];
  const float* W_key  = (const float*)d_in[6];
  const float* b_key  = (const float*)d_in[7];
  const float* W_beta = (const float*)d_in[8];
  const float* b_beta = (const float*)d_in[9];
  const float* W_gen  = (const float*)d_in[10];
  const float* b_gen  = (const float*)d_in[11];
  float* out = (float*)d_out;

  float* ws    = (float*)d_ws;
  float* W2p   = ws;                 // 1,703,936
  float* hbuf  = W2p  + 1703936;     //    32,768
  float* AccP  = hbuf + 32768;       //    16,384
  float* ZP    = AccP + 16384;       //       256
  float* S2P   = ZP   + 256;         //       256
  unsigned* ctr = (unsigned*)(S2P + 256);  // 1024 u32

  hipMemsetAsync(ctr, 0, 1024 * sizeof(unsigned), stream);
  hipMemsetAsync(out + 8388608, 0, sizeof(float), stream);

  build_w2p<<<dim3(6656), dim3(256), 0, stream>>>(W_ih, W_hh, W2p);

  P3 prm;
  prm.W2p = W2p;      prm.b_lstm = b_lstm;
  prm.W_out = W_out;  prm.b_out = b_out;
  prm.W_key = W_key;  prm.b_key = b_key;
  prm.W_beta = W_beta; prm.b_beta = b_beta;
  prm.W_gen = W_gen;  prm.b_gen = b_gen;
  prm.xs = xs;
  prm.hbuf = hbuf; prm.AccP = AccP; prm.ZP = ZP; prm.S2P = S2P;
  prm.ctr = ctr;  prm.out = out;

  void* kargs[] = { &prm };
  hipLaunchCooperativeKernel(reinterpret_cast<void*>(&dnc_b4),
                             dim3(256), dim3(1024), kargs, 0, stream);
}

// Round 4
// 13366.362 us; speedup vs baseline: 4.6773x; 1.3547x over previous
//
#include <hip/hip_runtime.h>
#include <hip/hip_fp16.h>

#define EPSF 1e-8f
#define SCOPE_AGT __HIP_MEMORY_SCOPE_AGENT

// T=512 B=64 IN=256 OUT=256 H=512 N=2048 C=64 R=4
// 256 blocks x 1024 threads (1/CU, cooperative co-residency), 4 blocks/batch.
// mem in registers (32 VGPR/thread). Cross-XCD exchange is FENCE-FREE:
// relaxed agent-scope atomics (sc0 sc1 -> coherent at L3) for payloads,
// RELEASE only on the counter post -> L2 weight cache never invalidated.

struct P4 {
  const unsigned* W2h;  // [4][416 rowpairs][512 cc] packed half2 {row 2rp, 2rp+1}
  const float* b_lstm;  // 2048
  const float* W_out;   // [512][256]
  const float* b_out;   // 256
  const float* W_key;   // [512][64]
  const float* b_key;   // 64
  const float* W_beta;  // 512
  const float* b_beta;  // 1
  const float* W_gen;   // [512][64]
  const float* b_gen;   // 64
  const float* xs;      // [512][64][256]
  float* hbuf;          // [64][512]
  float* keyP;          // [64][4][64]
  float* genP;          // [64][4][64]
  float* yP;            // [64][4][256]
  float* betaP;         // [64][4]
  float* AccP;          // [64][4][64]
  float* ZP;            // [64][4]
  float* S2P;           // [64][4]
  unsigned* ctr;        // [64][32]
  float* out;           // [512][64][256] + loss at 8388608
};

__device__ __forceinline__ float sigm(float x) { return 1.f / (1.f + __expf(-x)); }
__device__ __forceinline__ float aload(const float* p) {
  return __hip_atomic_load(p, __ATOMIC_RELAXED, SCOPE_AGT);
}
__device__ __forceinline__ void astore(float* p, float v) {
  __hip_atomic_store(p, v, __ATOMIC_RELAXED, SCOPE_AGT);
}

__global__ void __launch_bounds__(1024, 4) dnc_b4(P4 P) {
  const int tid   = threadIdx.x;
  const int bid   = blockIdx.x;
  const int chunk = (bid >> 1) & 3;                 // XCD(bid%8) hosts one chunk value
  const int b     = ((bid >> 3) << 1) | (bid & 1);
  const int lane  = tid & 63;
  const int wv    = tid >> 6;
  const int sgrp  = lane >> 4;
  const int c4    = lane & 15;

  __shared__ float s_inp[832];     // [x(256) | h(512) | r(64)]
  __shared__ float s_gates[512];
  __shared__ float s_c[128];
  __shared__ float s_part[4096];
  __shared__ float s_e[512];
  __shared__ float s_key[64], s_kprev[64], s_genv[64];
  __shared__ float s_wred[32];
  __shared__ float s_scal[4];      // 0:invZ_prev 1:S2_prev 2:beta 3:||key||

  unsigned* ctr = P.ctr + b * 32;

  float4 mreg[8];                  // own 512 slots
  float  sden[8];
#pragma unroll
  for (int i = 0; i < 8; ++i) mreg[i] = make_float4(0.f, 0.f, 0.f, 0.f);

  for (int i = 256 + tid; i < 832; i += 1024) s_inp[i] = 0.f;
  if (tid < 128) s_c[tid] = 0.f;
  if (tid < 512) s_e[tid] = 0.f;
  if (tid < 64)  s_kprev[tid] = 0.f;
  float lossacc = 0.f;
  __syncthreads();

  const int q  = tid >> 7;         // 0..7 rowpair-chunk
  const int cg = tid & 127;        // col-group (4 cols)
  const unsigned* wbase = P.W2h + (size_t)chunk * 212992 + (cg << 2);

  for (int t = 0; t < 512; ++t) {
    // ---- load x_t
    if (tid < 128)
      ((float2*)s_inp)[tid] = ((const float2*)P.xs)[((size_t)t * 64 + b) * 128 + tid];
    __syncthreads();

    // ---- GEMV part 1: rowpairs [q*48,+48) (x+h rows; no barrier needed)
    float4 acc = make_float4(0.f, 0.f, 0.f, 0.f);
    {
      const unsigned* wp = wbase + (size_t)(q * 48) * 512;
      const float* ip = s_inp + q * 96;
#pragma unroll 4
      for (int r = 0; r < 48; ++r) {
        const uint4 w = *(const uint4*)(wp + (size_t)r * 512);
        const float2 v = *(const float2*)(ip + r * 2);
        const __half2* h2 = (const __half2*)&w;
        const float2 f0 = __half22float2(h2[0]), f1 = __half22float2(h2[1]);
        const float2 f2 = __half22float2(h2[2]), f3 = __half22float2(h2[3]);
        acc.x = fmaf(v.x, f0.x, fmaf(v.y, f0.y, acc.x));
        acc.y = fmaf(v.x, f1.x, fmaf(v.y, f1.y, acc.y));
        acc.z = fmaf(v.x, f2.x, fmaf(v.y, f2.y, acc.z));
        acc.w = fmaf(v.x, f3.x, fmaf(v.y, f3.y, acc.w));
      }
    }

    // ---- C: wait barrier B_{t-1}; finalize r_{t-1}
    if (t > 0) {
      if (tid == 0) {
        while (__hip_atomic_load(ctr, __ATOMIC_RELAXED, SCOPE_AGT) < 8u * (unsigned)t)
          __builtin_amdgcn_s_sleep(1);
      }
      __syncthreads();
      float a0 = 0.f, a1 = 0.f, a2 = 0.f, a3 = 0.f;
      if (tid < 64) {
        const float* ap = P.AccP + b * 256 + tid;
        a0 = aload(ap); a1 = aload(ap + 64); a2 = aload(ap + 128); a3 = aload(ap + 192);
      } else if (tid == 64) {
        const float* zp = P.ZP + b * 4;
        const float* sp = P.S2P + b * 4;
        const float Z  = aload(zp) + aload(zp + 1) + aload(zp + 2) + aload(zp + 3);
        const float S2 = aload(sp) + aload(sp + 1) + aload(sp + 2) + aload(sp + 3);
        s_scal[0] = 1.f / Z;  s_scal[1] = S2;
      }
      __syncthreads();
      if (tid < 64) {
        const float iZ = s_scal[0];
        s_inp[768 + tid] = iZ * ((a0 + a1 + a2 + a3) + s_scal[1] * iZ * s_kprev[tid]);
      }
      __syncthreads();
    } else {
      if (tid == 64) { s_scal[0] = 0.f; s_scal[1] = 0.f; }  // r pre-zeroed
      __syncthreads();
    }

    // ---- GEMV part 2: rowpairs [384+q*4,+4) (r rows)
    {
      const unsigned* wp = wbase + (size_t)(384 + q * 4) * 512;
      const float* ip = s_inp + 768 + q * 8;
#pragma unroll
      for (int r = 0; r < 4; ++r) {
        const uint4 w = *(const uint4*)(wp + (size_t)r * 512);
        const float2 v = *(const float2*)(ip + r * 2);
        const __half2* h2 = (const __half2*)&w;
        const float2 f0 = __half22float2(h2[0]), f1 = __half22float2(h2[1]);
        const float2 f2 = __half22float2(h2[2]), f3 = __half22float2(h2[3]);
        acc.x = fmaf(v.x, f0.x, fmaf(v.y, f0.y, acc.x));
        acc.y = fmaf(v.x, f1.x, fmaf(v.y, f1.y, acc.y));
        acc.z = fmaf(v.x, f2.x, fmaf(v.y, f2.y, acc.z));
        acc.w = fmaf(v.x, f3.x, fmaf(v.y, f3.y, acc.w));
      }
    }
    *(float4*)&s_part[(q << 9) + (cg << 2)] = acc;
    __syncthreads();

    // ---- gates reduce + LSTM -> h_t (own 128 j), publish h chunk
    if (tid < 512) {
      s_gates[tid] = s_part[tid]        + s_part[512 + tid]  + s_part[1024 + tid] + s_part[1536 + tid]
                   + s_part[2048 + tid] + s_part[2560 + tid] + s_part[3072 + tid] + s_part[3584 + tid];
    }
    __syncthreads();
    if (tid < 128) {
      const int jl = tid, cb = chunk * 128 + jl;
      const float gi = s_gates[jl * 4 + 0] + P.b_lstm[cb];
      const float gf = s_gates[jl * 4 + 1] + P.b_lstm[512 + cb];
      const float gg = s_gates[jl * 4 + 2] + P.b_lstm[1024 + cb];
      const float go = s_gates[jl * 4 + 3] + P.b_lstm[1536 + cb];
      const float cn = sigm(gf) * s_c[jl] + sigm(gi) * tanhf(gg);
      s_c[jl] = cn;
      const float hn = sigm(go) * tanhf(cn);
      s_inp[256 + cb] = hn;
      astore(P.hbuf + b * 512 + cb, hn);
    }
    __syncthreads();

    // ---- E2: own-h-row projection partials (rows [chunk*128,+128))
    {
      const float* h = s_inp + 256 + chunk * 128;
      {  // keyP (tid<512) / genP (tid>=512): 8 rowgroups x 64 cols, 16 rows each
        const int isg = tid >> 9, rg = (tid >> 6) & 7, c = tid & 63;
        const float* W = isg ? P.W_gen : P.W_key;
        const float* wp2 = W + (size_t)(chunk * 128 + rg * 16) * 64 + c;
        const float* hh = h + rg * 16;
        float a2 = 0.f;
#pragma unroll
        for (int r2 = 0; r2 < 16; ++r2) a2 = fmaf(hh[r2], wp2[(size_t)r2 * 64], a2);
        s_part[tid] = a2;
      }
      {  // yP: 4 rowgroups x 256 cols, 32 rows each
        const int rg = tid >> 8, col = tid & 255;
        const float* wp2 = P.W_out + (size_t)(chunk * 128 + rg * 32) * 256 + col;
        const float* hh = h + rg * 32;
        float a2 = 0.f;
#pragma unroll 8
        for (int r2 = 0; r2 < 32; ++r2) a2 = fmaf(hh[r2], wp2[(size_t)r2 * 256], a2);
        s_part[1024 + (rg << 8) + col] = a2;
      }
      {  // betaP: own 128 rows (waves 0,1)
        float pb = (tid < 128) ? h[tid] * P.W_beta[chunk * 128 + tid] : 0.f;
#pragma unroll
        for (int off = 32; off; off >>= 1) pb += __shfl_down(pb, off);
        if (tid < 128 && lane == 0) s_wred[wv] = pb;
      }
    }
    __syncthreads();
    // ---- E3: reduce + publish partials
    if (tid < 64) {
      float v = 0.f;
#pragma unroll
      for (int k = 0; k < 8; ++k) v += s_part[k * 64 + tid];
      astore(P.keyP + (b * 4 + chunk) * 64 + tid, v);
    } else if (tid < 128) {
      const int c = tid - 64;
      float v = 0.f;
#pragma unroll
      for (int k = 0; k < 8; ++k) v += s_part[512 + k * 64 + c];
      astore(P.genP + (b * 4 + chunk) * 64 + c, v);
    } else if (tid < 384) {
      const int col = tid - 128;
      astore(P.yP + (b * 4 + chunk) * 256 + col,
             s_part[1024 + col] + s_part[1280 + col] + s_part[1536 + col] + s_part[1792 + col]);
    } else if (tid == 384) {
      astore(P.betaP + b * 4 + chunk, s_wred[0] + s_wred[1]);
    }
    __syncthreads();                              // drains stores (vmcnt) before post
    if (tid == 0) __hip_atomic_fetch_add(ctr, 1u, __ATOMIC_RELEASE, SCOPE_AGT);  // post A

    // ---- G1 (in barrier-A shadow): apply pending rank-1 update; slot norms
    {
      const float invZp = s_scal[0];
      const float4 kp4 = ((const float4*)s_kprev)[c4];
      const int nbase = (wv * 4 + sgrp) * 8;
#pragma unroll
      for (int it = 0; it < 8; ++it) {
        float4 m4 = mreg[it];
        const float wpv = s_e[nbase + it] * invZp;   // w_{t-1}[n]  (0 at t=0)
        m4.x = fmaf(wpv, kp4.x, m4.x); m4.y = fmaf(wpv, kp4.y, m4.y);
        m4.z = fmaf(wpv, kp4.z, m4.z); m4.w = fmaf(wpv, kp4.w, m4.w);
        float ssq = m4.x * m4.x + m4.y * m4.y + m4.z * m4.z + m4.w * m4.w;
#pragma unroll
        for (int off = 1; off < 16; off <<= 1) ssq += __shfl_xor(ssq, off);
        sden[it] = fmaxf(sqrtf(ssq), EPSF);
        mreg[it] = m4;
      }
    }

    // ---- F: wait A; assemble key/gen/y/beta; fetch peers' h
    if (tid == 0) {
      while (__hip_atomic_load(ctr, __ATOMIC_RELAXED, SCOPE_AGT) < 8u * (unsigned)t + 4u)
        __builtin_amdgcn_s_sleep(1);
    }
    __syncthreads();
    if (tid < 64) {
      const float* kp = P.keyP + b * 256 + tid;
      s_key[tid] = aload(kp) + aload(kp + 64) + aload(kp + 128) + aload(kp + 192) + P.b_key[tid];
    } else if (tid < 128) {
      const int c = tid - 64;
      const float* gp = P.genP + b * 256 + c;
      s_genv[c] = aload(gp) + aload(gp + 64) + aload(gp + 128) + aload(gp + 192) + P.b_gen[c];
    } else if (tid < 192) {
      const int col = tid - 128, oc = chunk * 64 + col;
      const float* yp = P.yP + b * 1024 + oc;
      P.out[((size_t)t * 64 + b) * 256 + oc] =
          aload(yp) + aload(yp + 256) + aload(yp + 512) + aload(yp + 768) + P.b_out[oc];
    } else if (tid == 192) {
      const float* bp = P.betaP + b * 4;
      const float s = aload(bp) + aload(bp + 1) + aload(bp + 2) + aload(bp + 3) + P.b_beta[0];
      s_scal[2] = (s > 20.f) ? s : log1pf(__expf(s));   // softplus
    } else if (tid >= 256 && tid < 640) {
      const int i = tid - 256;
      const int pc = i >> 7;
      const int pcc = pc + (pc >= chunk ? 1 : 0);       // peer chunks
      const int jl = i & 127;
      s_inp[256 + pcc * 128 + jl] = aload(P.hbuf + b * 512 + pcc * 128 + jl);
    }
    __syncthreads();
    if (wv == 0) {
      const float kv = s_key[lane];
      float sq = kv * kv;
#pragma unroll
      for (int off = 32; off; off >>= 1) sq += __shfl_down(sq, off);
      if (lane == 0) s_scal[3] = fmaxf(sqrtf(sq), EPSF);
    } else if (wv == 1 && chunk == 0) {
      const float d = s_key[lane] - s_genv[lane];
      float ds = d * d;
#pragma unroll
      for (int off = 32; off; off >>= 1) ds += __shfl_down(ds, off);
      if (lane == 0) lossacc += ds;                      // tid 64
    }
    __syncthreads();

    // ---- G2: sim/exp/acc on updated mem (registers)
    {
      const float beta = s_scal[2], kn = s_scal[3];
      const float4 kk = ((const float4*)s_key)[c4];
      float Zp = 0.f, S2p = 0.f;
      float4 acc4 = make_float4(0.f, 0.f, 0.f, 0.f);
      const int nbase = (wv * 4 + sgrp) * 8;
#pragma unroll
      for (int it = 0; it < 8; ++it) {
        const float4 m4 = mreg[it];
        float num = m4.x * kk.x + m4.y * kk.y + m4.z * kk.z + m4.w * kk.w;
#pragma unroll
        for (int off = 1; off < 16; off <<= 1) num += __shfl_xor(num, off);
        const float e = __expf(beta * (num / (sden[it] * kn)));
        if (c4 == 0) { s_e[nbase + it] = e; Zp += e; S2p += e * e; }
        acc4.x = fmaf(e, m4.x, acc4.x); acc4.y = fmaf(e, m4.y, acc4.y);
        acc4.z = fmaf(e, m4.z, acc4.z); acc4.w = fmaf(e, m4.w, acc4.w);
      }
#pragma unroll
      for (int off = 32; off; off >>= 1) { Zp += __shfl_down(Zp, off); S2p += __shfl_down(S2p, off); }
      if (lane == 0) { s_wred[wv] = Zp; s_wred[16 + wv] = S2p; }
#pragma unroll
      for (int off = 16; off < 64; off <<= 1) {
        acc4.x += __shfl_down(acc4.x, off); acc4.y += __shfl_down(acc4.y, off);
        acc4.z += __shfl_down(acc4.z, off); acc4.w += __shfl_down(acc4.w, off);
      }
      if (lane < 16) ((float4*)s_part)[wv * 16 + lane] = acc4;
    }
    __syncthreads();
    if (tid < 64) {
      float a = 0.f;
#pragma unroll
      for (int w = 0; w < 16; ++w) a += s_part[w * 64 + tid];
      astore(P.AccP + (b * 4 + chunk) * 64 + tid, a);
      s_kprev[tid] = s_key[tid];
    } else if (tid == 64) {
      float Z = 0.f, S2 = 0.f;
#pragma unroll
      for (int k = 0; k < 16; ++k) { Z += s_wred[k]; S2 += s_wred[16 + k]; }
      astore(P.ZP + b * 4 + chunk, Z);
      astore(P.S2P + b * 4 + chunk, S2);
    }
    __syncthreads();                              // drains stores before post
    if (tid == 0) __hip_atomic_fetch_add(ctr, 1u, __ATOMIC_RELEASE, SCOPE_AGT);  // post B
  }

  if (chunk == 0 && tid == 64) atomicAdd(P.out + 8388608, lossacc * (1.f / 4096.f));
}

// W2h[chunk][rp][cc] = half2{W[2rp][col], W[2rp+1][col]}, col = g*512 + chunk*128 + jl,
// cc = jl*4+g. rows [0,256)=W_ih(x), [256,768)=W_hh, [768,832)=W_ih read-rows folded (R=4).
__global__ void build_w2h(const float* __restrict__ W_ih, const float* __restrict__ W_hh,
                          unsigned* __restrict__ W2h) {
  const int id = blockIdx.x * 256 + threadIdx.x;   // over 4*416*512
  if (id >= 851968) return;
  const int chunk = id / 212992;
  const int rem   = id % 212992;
  const int rp    = rem >> 9;
  const int cc    = rem & 511;
  const int jl = cc >> 2, g = cc & 3;
  const int col = g * 512 + chunk * 128 + jl;
  float v[2];
#pragma unroll
  for (int k = 0; k < 2; ++k) {
    const int row = rp * 2 + k;
    if (row < 256)      v[k] = W_ih[(size_t)row * 2048 + col];
    else if (row < 768) v[k] = W_hh[(size_t)(row - 256) * 2048 + col];
    else {
      const float* p0 = W_ih + (size_t)(256 + (row - 768) * 4) * 2048 + col;
      v[k] = p0[0] + p0[2048] + p0[4096] + p0[6144];
    }
  }
  const __half2 h2 = __floats2half2_rn(v[0], v[1]);
  W2h[id] = *(const unsigned*)&h2;
}

extern "C" void kernel_launch(void* const* d_in, const int* in_sizes, int n_in,
                              void* d_out, int out_size, void* d_ws, size_t ws_size,
                              hipStream_t stream) {
  const float* xs     = (const float*)d_in[0];
  const float* W_ih   = (const float*)d_in[1];
  const float* W_hh   = (const float*)d_in[2];
  const float* b_lstm = (const float*)d_in[3];
  const float* W_out  = (const float*)d_in[4];
  const float* b_out  = (const float*)d_in[5];
  const float* W_key  = (const float*)d_in[6];
  const float* b_key  = (const float*)d_in[7];
  const float* W_beta = (const float*)d_in[8];
  const float* b_beta = (const float*)d_in[9];
  const float* W_gen  = (const float*)d_in[10];
  const float* b_gen  = (const float*)d_in[11];
  float* out = (float*)d_out;

  float* ws = (float*)d_ws;
  unsigned* W2h = (unsigned*)ws;          //   851,968 u32
  float* hbuf  = ws     + 851968;         //    32,768
  float* keyP  = hbuf   + 32768;          //    16,384
  float* genP  = keyP   + 16384;          //    16,384
  float* yP    = genP   + 16384;          //    65,536
  float* betaP = yP     + 65536;          //       256
  float* AccP  = betaP  + 256;            //    16,384
  float* ZP    = AccP   + 16384;          //       256
  float* S2P   = ZP     + 256;            //       256
  unsigned* ctr = (unsigned*)(S2P + 256); //     2,048 u32

  hipMemsetAsync(ctr, 0, 2048 * sizeof(unsigned), stream);
  hipMemsetAsync(out + 8388608, 0, sizeof(float), stream);

  build_w2h<<<dim3(3328), dim3(256), 0, stream>>>(W_ih, W_hh, W2h);

  P4 prm;
  prm.W2h = W2h;      prm.b_lstm = b_lstm;
  prm.W_out = W_out;  prm.b_out = b_out;
  prm.W_key = W_key;  prm.b_key = b_key;
  prm.W_beta = W_beta; prm.b_beta = b_beta;
  prm.W_gen = W_gen;  prm.b_gen = b_gen;
  prm.xs = xs;
  prm.hbuf = hbuf; prm.keyP = keyP; prm.genP = genP; prm.yP = yP; prm.betaP = betaP;
  prm.AccP = AccP; prm.ZP = ZP; prm.S2P = S2P;
  prm.ctr = ctr;  prm.out = out;

  void* kargs[] = { &prm };
  hipLaunchCooperativeKernel(reinterpret_cast<void*>(&dnc_b4),
                             dim3(256), dim3(1024), kargs, 0, stream);
}